// Round 18
// baseline (254.068 us; speedup 1.0000x reference)
//
#include <hip/hip_runtime.h>
#include <stdint.h>

#define B_ 2
#define T_ 2048
#define C_ 2048
#define H_ 16
#define D_ 128
#define W_ 512
#define M_ (B_*T_)      // 4096
#define N1_ (3*C_)      // 6144

typedef short bf16x8 __attribute__((ext_vector_type(8)));
typedef unsigned short u16x8 __attribute__((ext_vector_type(8)));
typedef float f32x4 __attribute__((ext_vector_type(4)));

#define SB() __builtin_amdgcn_sched_barrier(0)

__device__ __forceinline__ unsigned short f2bf(float f) {
  union { float f; unsigned u; } v; v.f = f;
  unsigned r = v.u + 0x7fffu + ((v.u >> 16) & 1u);
  return (unsigned short)(r >> 16);
}
__device__ __forceinline__ float bf2f(unsigned short b) {
  union { unsigned u; float f; } v; v.u = ((unsigned)b) << 16;
  return v.f;
}

__device__ __forceinline__ void gload_lds16(const void* g, void* l) {
  __builtin_amdgcn_global_load_lds((const __attribute__((address_space(1))) void*)g,
                                   (__attribute__((address_space(3))) void*)l, 16, 0, 0);
}

// ---------- fp32 -> bf16 convert ----------
__global__ void k_cvt(const float* __restrict__ s, unsigned short* __restrict__ d, int n) {
  int i = (blockIdx.x * blockDim.x + threadIdx.x) * 8;
  if (i >= n) return;
  float4 a = *(const float4*)(s + i);
  float4 b = *(const float4*)(s + i + 4);
  u16x8 o;
  o[0]=f2bf(a.x); o[1]=f2bf(a.y); o[2]=f2bf(a.z); o[3]=f2bf(a.w);
  o[4]=f2bf(b.x); o[5]=f2bf(b.y); o[6]=f2bf(b.z); o[7]=f2bf(b.w);
  *(u16x8*)(d + i) = o;
}

// ---------- transpose + convert: src [R][Cc] f32 -> dst [Cc][R] bf16 ----------
__global__ void k_tcvt(const float* __restrict__ s, unsigned short* __restrict__ d, int R, int Cc) {
  __shared__ float tile[32][33];
  int c0 = blockIdx.x * 32, r0 = blockIdx.y * 32;
  int tx = threadIdx.x & 31, ty = threadIdx.x >> 5;
  #pragma unroll
  for (int j = 0; j < 32; j += 8) tile[ty + j][tx] = s[(size_t)(r0 + ty + j) * Cc + c0 + tx];
  __syncthreads();
  #pragma unroll
  for (int j = 0; j < 32; j += 8) d[(size_t)(c0 + ty + j) * R + r0 + tx] = f2bf(tile[tx][ty + j]);
}

// ---------- staging helper (512-thread blocks): st_16x32 XOR swizzle ----------
template<int ROWS, int K>
__device__ __forceinline__ void stage_half(const unsigned short* __restrict__ gbase,
                                           int row0, int kt, int kh,
                                           unsigned short* region, int tid, int sw) {
  const char* gsrc = (const char*)(gbase + (size_t)row0 * K + kt * 64 + kh * 32);
  {
    int o = tid * 16, s = o ^ sw;
    gload_lds16(gsrc + (size_t)(s >> 6) * (K * 2) + (s & 63), (char*)region + o);
  }
  if (ROWS == 256) {
    int o = (512 + tid) * 16, s = o ^ sw;
    gload_lds16(gsrc + (size_t)(s >> 6) * (K * 2) + (s & 63), (char*)region + o);
  }
}

// ---------- GEMM1 fused: 256x256 4-phase (R8 schedule) + RoPE epilogue ------
template<int K, int Ntot>
__global__ __launch_bounds__(512, 2) void k_gemmF(const unsigned short* __restrict__ A,
                                                  const unsigned short* __restrict__ Bt,
                                                  const float* __restrict__ fcos,
                                                  const float* __restrict__ fsin,
                                                  unsigned short* __restrict__ q_r,
                                                  unsigned short* __restrict__ k_r,
                                                  unsigned short* __restrict__ vq) {
  __shared__ unsigned short As[2][2][256 * 32];
  __shared__ unsigned short Bs[2][2][256 * 32];
  const int tid = threadIdx.x, lane = tid & 63, wv = tid >> 6;
  const int wm = wv >> 2, wn = wv & 3;
  const int lr = lane & 15, lg = lane >> 4;
  const int sw = tid & 32;
  const int fofs = lr * 64 + ((lg * 16) ^ ((lr & 8) << 2));
  const int aoff = wm * 128 * 64 + fofs;
  int bofs[4];
  #pragma unroll
  for (int j = 0; j < 4; ++j)
    bofs[j] = ((wn >> 1) * 128 + (wn & 1) * 32 + (j >> 1) * 64 + (j & 1) * 16) * 64 + fofs;

  const int nwg = gridDim.x;
  const int nbx = Ntot >> 8;
  const int q = nwg >> 3, r = nwg & 7;
  const int xcd = blockIdx.x & 7, off = blockIdx.x >> 3;
  const int bid = (xcd < r ? xcd * (q + 1) : r * (q + 1) + (xcd - r) * q) + off;
  const int bm0 = (bid / nbx) << 8;
  const int bn0 = (bid % nbx) << 8;

  f32x4 acc[8][4];
  #pragma unroll
  for (int i = 0; i < 8; ++i)
    #pragma unroll
    for (int j = 0; j < 4; ++j)
      #pragma unroll
      for (int e = 0; e < 4; ++e) acc[i][j][e] = 0.f;

  constexpr int NT = K >> 6;

  stage_half<256, K>(A,  bm0, 0, 0, As[0][0], tid, sw);
  stage_half<256, K>(Bt, bn0, 0, 0, Bs[0][0], tid, sw);
  stage_half<256, K>(Bt, bn0, 0, 1, Bs[0][1], tid, sw);
  stage_half<256, K>(A,  bm0, 0, 1, As[0][1], tid, sw);
  stage_half<256, K>(Bt, bn0, 1, 0, Bs[1][0], tid, sw);
  stage_half<256, K>(A,  bm0, 1, 0, As[1][0], tid, sw);
  stage_half<256, K>(Bt, bn0, 1, 1, Bs[1][1], tid, sw);
  asm volatile("s_waitcnt vmcnt(4)" ::: "memory");
  __builtin_amdgcn_s_barrier();

  bf16x8 Xa[4], Xb[4], Ya[4];
  #pragma unroll
  for (int j = 0; j < 4; ++j) Xb[j] = *(const bf16x8*)((const char*)Bs[0][0] + bofs[j]);
  #pragma unroll
  for (int i = 0; i < 4; ++i) Xa[i] = *(const bf16x8*)((const char*)As[0][0] + aoff + i * 1024);

  #pragma unroll 2
  for (int t = 0; t < NT; ++t) {
    const int p = t & 1;
    // ---- ph0 ----
    asm volatile("s_waitcnt lgkmcnt(0)" ::: "memory");
    SB();
    __builtin_amdgcn_s_setprio(1);
    #pragma unroll
    for (int i = 0; i < 4; ++i)
      #pragma unroll
      for (int j = 0; j < 4; ++j)
        acc[i][j] = __builtin_amdgcn_mfma_f32_16x16x32_bf16(Xa[i], Xb[j], acc[i][j], 0, 0, 0);
    __builtin_amdgcn_s_setprio(0);
    #pragma unroll
    for (int i = 0; i < 4; ++i) Ya[i] = *(const bf16x8*)((const char*)As[p][0] + aoff + (i + 4) * 1024);
    if (t + 1 < NT) stage_half<256, K>(A, bm0, t + 1, 1, As[p ^ 1][1], tid, sw);
    __builtin_amdgcn_s_barrier();

    // ---- ph1 ----
    asm volatile("s_waitcnt lgkmcnt(0)" ::: "memory");
    SB();
    __builtin_amdgcn_s_setprio(1);
    #pragma unroll
    for (int i = 0; i < 4; ++i)
      #pragma unroll
      for (int j = 0; j < 4; ++j)
        acc[i + 4][j] = __builtin_amdgcn_mfma_f32_16x16x32_bf16(Ya[i], Xb[j], acc[i + 4][j], 0, 0, 0);
    __builtin_amdgcn_s_setprio(0);
    #pragma unroll
    for (int j = 0; j < 4; ++j) Xb[j] = *(const bf16x8*)((const char*)Bs[p][1] + bofs[j]);
    #pragma unroll
    for (int i = 0; i < 4; ++i) Xa[i] = *(const bf16x8*)((const char*)As[p][1] + aoff + i * 1024);
    if (t + 2 < NT) stage_half<256, K>(Bt, bn0, t + 2, 0, Bs[p][0], tid, sw);
    __builtin_amdgcn_s_barrier();

    // ---- ph2 ----
    asm volatile("s_waitcnt lgkmcnt(0)" ::: "memory");
    SB();
    __builtin_amdgcn_s_setprio(1);
    #pragma unroll
    for (int i = 0; i < 4; ++i)
      #pragma unroll
      for (int j = 0; j < 4; ++j)
        acc[i][j] = __builtin_amdgcn_mfma_f32_16x16x32_bf16(Xa[i], Xb[j], acc[i][j], 0, 0, 0);
    __builtin_amdgcn_s_setprio(0);
    #pragma unroll
    for (int i = 0; i < 4; ++i) Ya[i] = *(const bf16x8*)((const char*)As[p][1] + aoff + (i + 4) * 1024);
    if (t + 2 < NT) stage_half<256, K>(A, bm0, t + 2, 0, As[p][0], tid, sw);
    __builtin_amdgcn_s_barrier();

    // ---- ph3 ----
    asm volatile("s_waitcnt lgkmcnt(0)" ::: "memory");
    SB();
    __builtin_amdgcn_s_setprio(1);
    #pragma unroll
    for (int i = 0; i < 4; ++i)
      #pragma unroll
      for (int j = 0; j < 4; ++j)
        acc[i + 4][j] = __builtin_amdgcn_mfma_f32_16x16x32_bf16(Ya[i], Xb[j], acc[i + 4][j], 0, 0, 0);
    __builtin_amdgcn_s_setprio(0);
    if (t < NT - 2) asm volatile("s_waitcnt vmcnt(4)" ::: "memory");
    else            asm volatile("s_waitcnt vmcnt(0)" ::: "memory");
    #pragma unroll
    for (int j = 0; j < 4; ++j) Xb[j] = *(const bf16x8*)((const char*)Bs[p ^ 1][0] + bofs[j]);
    #pragma unroll
    for (int i = 0; i < 4; ++i) Xa[i] = *(const bf16x8*)((const char*)As[p ^ 1][0] + aoff + i * 1024);
    if (t + 2 < NT) stage_half<256, K>(Bt, bn0, t + 2, 1, Bs[p][1], tid, sw);
    __builtin_amdgcn_s_barrier();
  }
  asm volatile("s_waitcnt lgkmcnt(0)" ::: "memory");

  // ---------- fused epilogue ----------
  const int nb  = bn0 >> 11;        // 0=q, 1=k, 2=v
  const int rem = bn0 & 2047;
  const int b   = bm0 >> 11;
  const int t0  = bm0 & 2047;
  const int wcb = (wn >> 1) * 128 + (wn & 1) * 32;

  if (nb == 2) {
    #pragma unroll
    for (int i = 0; i < 8; ++i)
      #pragma unroll
      for (int j = 0; j < 4; ++j) {
        int col = rem + wcb + (j >> 1) * 64 + (j & 1) * 16 + lr;
        #pragma unroll
        for (int e = 0; e < 4; ++e) {
          int t = t0 + wm * 128 + i * 16 + lg * 4 + e;
          vq[((size_t)(b * T_ + t)) * C_ + col] = f2bf(acc[i][j][e]);
        }
      }
  } else {
    unsigned short* dst = nb ? k_r : q_r;
    #pragma unroll
    for (int i = 0; i < 8; ++i)
      #pragma unroll
      for (int j = 0; j < 4; ++j) {
        int col = rem + wcb + (j >> 1) * 64 + (j & 1) * 16 + lr;
        int head = col >> 7, d = col & 127;
        float sgn = (j < 2) ? -1.f : 1.f;
        #pragma unroll
        for (int e = 0; e < 4; ++e) {
          int t = t0 + wm * 128 + i * 16 + lg * 4 + e;
          float c = fcos[t * D_ + d];
          float s = fsin[t * D_ + d];
          float out = acc[i][j][e] * c + sgn * acc[i][j ^ 2][e] * s;
          dst[((size_t)(b * H_ + head) * T_ + t) * D_ + d] = f2bf(out);
        }
      }
  }
}

// ---------- GEMM2: 128x128 tile, 8 waves, dbuf, 2 blocks/CU (R14) ----------
template<int K, int Ntot>
__global__ __launch_bounds__(512, 4) void k_gemmS(const unsigned short* __restrict__ A,
                                                  const unsigned short* __restrict__ Bt,
                                                  float* __restrict__ Cp) {
  __shared__ unsigned short As[2][2][128 * 32];
  __shared__ unsigned short Bs[2][2][128 * 32];
  const int tid = threadIdx.x, lane = tid & 63, wv = tid >> 6;
  const int wm = wv >> 1, wn = wv & 1;
  const int lr = lane & 15, lg = lane >> 4;
  const int sw = tid & 32;
  const int fofs = lr * 64 + ((lg * 16) ^ ((lr & 8) << 2));
  const int aoff = wm * 32 * 64 + fofs;
  const int boff = wn * 64 * 64 + fofs;

  const int nwg = gridDim.x;
  const int nbx = Ntot >> 7;
  const int q = nwg >> 3, r = nwg & 7;
  const int xcd = blockIdx.x & 7, off = blockIdx.x >> 3;
  const int bid = (xcd < r ? xcd * (q + 1) : r * (q + 1) + (xcd - r) * q) + off;
  const int bm0 = (bid / nbx) << 7;
  const int bn0 = (bid % nbx) << 7;

  f32x4 acc[2][4];
  #pragma unroll
  for (int i = 0; i < 2; ++i)
    #pragma unroll
    for (int j = 0; j < 4; ++j)
      #pragma unroll
      for (int e = 0; e < 4; ++e) acc[i][j][e] = 0.f;

  constexpr int NT = K >> 6;

  auto stage_tile = [&](int kt, int rr) {
    stage_half<128, K>(A,  bm0, kt, 0, As[rr][0], tid, sw);
    stage_half<128, K>(Bt, bn0, kt, 0, Bs[rr][0], tid, sw);
    stage_half<128, K>(A,  bm0, kt, 1, As[rr][1], tid, sw);
    stage_half<128, K>(Bt, bn0, kt, 1, Bs[rr][1], tid, sw);
  };

  stage_tile(0, 0);
  asm volatile("s_waitcnt vmcnt(0)" ::: "memory");
  __builtin_amdgcn_s_barrier();

  for (int t = 0; t < NT; ++t) {
    const int p = t & 1;
    if (t + 1 < NT) stage_tile(t + 1, p ^ 1);

    bf16x8 af[2], bfr[4];
    #pragma unroll
    for (int kh = 0; kh < 2; ++kh) {
      #pragma unroll
      for (int i = 0; i < 2; ++i) af[i] = *(const bf16x8*)((const char*)As[p][kh] + aoff + i * 1024);
      #pragma unroll
      for (int j = 0; j < 4; ++j) bfr[j] = *(const bf16x8*)((const char*)Bs[p][kh] + boff + j * 1024);
      asm volatile("s_waitcnt lgkmcnt(0)" ::: "memory");
      SB();
      __builtin_amdgcn_s_setprio(1);
      #pragma unroll
      for (int i = 0; i < 2; ++i)
        #pragma unroll
        for (int j = 0; j < 4; ++j)
          acc[i][j] = __builtin_amdgcn_mfma_f32_16x16x32_bf16(af[i], bfr[j], acc[i][j], 0, 0, 0);
      __builtin_amdgcn_s_setprio(0);
    }
    asm volatile("s_waitcnt vmcnt(0)" ::: "memory");
    __builtin_amdgcn_s_barrier();
  }

  #pragma unroll
  for (int i = 0; i < 2; ++i)
    #pragma unroll
    for (int j = 0; j < 4; ++j) {
      int m = bm0 + wm * 32 + i * 16 + lg * 4;
      int n = bn0 + wn * 64 + j * 16 + lr;
      #pragma unroll
      for (int e = 0; e < 4; ++e)
        Cp[(size_t)(m + e) * Ntot + n] = acc[i][j][e];
    }
}

// ---------- v transpose: vq (b,t,h,d) -> v_t (b,h,d,t) ----------
__global__ __launch_bounds__(256) void k_vt(const unsigned short* __restrict__ vq,
                                            unsigned short* __restrict__ v_t) {
  const int bh = blockIdx.x, b = bh >> 4, h = bh & 15;
  const int t0 = blockIdx.y * 64;
  const int tid = threadIdx.x;
  __shared__ unsigned short vt[64][136];
  #pragma unroll
  for (int p = 0; p < 4; ++p) {
    int idx = p * 256 + tid;
    int tl = idx >> 4, sg = idx & 15;
    int t = t0 + tl, d0 = sg * 8;
    *(u16x8*)&vt[tl][d0] = *(const u16x8*)(vq + (size_t)(b*T_ + t) * C_ + h*D_ + d0);
  }
  __syncthreads();
  #pragma unroll
  for (int p = 0; p < 4; ++p) {
    int idx = p * 256 + tid;
    int sg = idx & 7, d = idx >> 3;
    u16x8 o;
    #pragma unroll
    for (int e = 0; e < 8; ++e) o[e] = vt[sg*8 + e][d];
    *(u16x8*)(v_t + (size_t)((b*H_ + h)*D_ + d) * T_ + t0 + sg*8) = o;
  }
}

// ---------- attention: 16 waves, q=256/block, K dbuf + V single-buf ----------
// Per 256 q-rows: (512+256)/64 = 12 tiles vs 20 for q=128 -> 40% less staging
// and 40% fewer barrier phases. LDS 80KB (Ks 32 + Vs 16 + Ps 32), 1 block/CU,
// 16 waves = 4 waves/SIMD (same occupancy as 2x8-wave). 1024 thr -> 1 DMA tick
// per K/V tile: ledger: iter t issues V(t),K(t+1); vmcnt(1) drains K(t)+V(t)
// leaving K(t+1); last tile vmcnt(0). q-preloads oldest, drained first wait.
// V WAR sealed by tile-end lgkm(0)+barrier.
__global__ __launch_bounds__(1024, 4) void k_attn(const unsigned short* __restrict__ q_r,
                       const unsigned short* __restrict__ k_r,
                       const unsigned short* __restrict__ v_t,
                       unsigned short* __restrict__ y) {
  const int bh = blockIdx.x, b = bh >> 4, h = bh & 15;
  const int q0 = blockIdx.y * 256;
  const int tid = threadIdx.x, lane = tid & 63, wv = tid >> 6;
  const int lr = lane & 15, lg = lane >> 4;

  __shared__ unsigned short Ks[2][64 * 128];   // 32 KB
  __shared__ unsigned short Vs[128 * 64];      // 16 KB
  __shared__ unsigned short Ps[16 * 16 * 64];  // 32 KB

  const size_t bhT = (size_t)(b*H_ + h) * T_;
  const size_t bhD = (size_t)(b*H_ + h) * D_;
  const unsigned short* qbase = q_r + (bhT + q0 + wv*16 + lr) * D_;
  bf16x8 qf[4];
  #pragma unroll
  for (int kk = 0; kk < 4; ++kk) qf[kk] = *(const bf16x8*)(qbase + kk*32 + lg*8);

  f32x4 o[8];
  #pragma unroll
  for (int i = 0; i < 8; ++i)
    #pragma unroll
    for (int e = 0; e < 4; ++e) o[i][e] = 0.f;
  float m_run[4], l_sum[4];
  #pragma unroll
  for (int e = 0; e < 4; ++e) { m_run[e] = -1e30f; l_sum[e] = 0.f; }

  const int i_min = q0 + wv*16, i_max = i_min + 15;
  int kt_lo = q0 - (W_ - 1); if (kt_lo < 0) kt_lo = 0; kt_lo &= ~63;
  const float scale = 0.08838834764831845f;

  unsigned short* Ps_w = Ps + wv * 1024;

  auto stage_k = [&](int kt, int buf) {
    int ob = tid * 16;
    int row = ob >> 8, slot = (ob >> 4) & 15;
    int cb = slot ^ ((row & 7) << 1);
    gload_lds16(k_r + (bhT + kt + row) * D_ + cb * 8, (char*)Ks[buf] + ob);
  };
  auto stage_v = [&](int kt) {
    int ob = tid * 16;
    int d = ob >> 7, slot = (ob >> 4) & 7;
    int cb = slot ^ (d & 7);
    gload_lds16(v_t + (bhD + d) * T_ + kt + cb * 8, (char*)Vs + ob);
  };

  stage_k(kt_lo, 0);
  int cur = 0;
  for (int kt = kt_lo; kt < q0 + 256; kt += 64) {
    const bool has_next = (kt + 64 < q0 + 256);
    stage_v(kt);
    if (has_next) stage_k(kt + 64, cur ^ 1);
    if (has_next) asm volatile("s_waitcnt vmcnt(1)" ::: "memory");
    else          asm volatile("s_waitcnt vmcnt(0)" ::: "memory");
    __builtin_amdgcn_s_barrier();

    const bool live = (kt <= i_max) && (kt + 63 >= i_min - (W_ - 1));
    float sv[4][4];
    if (live) {
      const unsigned short* Kc = Ks[cur];
      f32x4 s[4];
      #pragma unroll
      for (int ct = 0; ct < 4; ++ct)
        #pragma unroll
        for (int e = 0; e < 4; ++e) s[ct][e] = 0.f;
      #pragma unroll
      for (int kk = 0; kk < 4; ++kk) {
        #pragma unroll
        for (int ct = 0; ct < 4; ++ct) {
          bf16x8 kf = *(const bf16x8*)&Kc[(ct*16 + lr)*128 + ((kk*4 + lg) ^ ((lr & 7) << 1))*8];
          s[ct] = __builtin_amdgcn_mfma_f32_16x16x32_bf16(qf[kk], kf, s[ct], 0, 0, 0);
        }
      }
      float mnew[4];
      int grow = 0;
      #pragma unroll
      for (int e = 0; e < 4; ++e) {
        int i = i_min + lg*4 + e;
        float rm = -1e30f;
        #pragma unroll
        for (int ct = 0; ct < 4; ++ct) {
          int j = kt + ct*16 + lr;
          bool ok = (j <= i) && (j > i - W_);
          sv[e][ct] = ok ? s[ct][e] * scale : -1e30f;
          rm = fmaxf(rm, sv[e][ct]);
        }
        #pragma unroll
        for (int msk = 1; msk < 16; msk <<= 1) rm = fmaxf(rm, __shfl_xor(rm, msk));
        mnew[e] = fmaxf(m_run[e], rm);
        grow |= (mnew[e] > m_run[e]) ? 1 : 0;
      }
      if (__any(grow)) {
        #pragma unroll
        for (int e = 0; e < 4; ++e) {
          float fac = __expf(m_run[e] - mnew[e]);
          l_sum[e] *= fac;
          m_run[e] = mnew[e];
          #pragma unroll
          for (int nt = 0; nt < 8; ++nt) o[nt][e] *= fac;
        }
      }
      #pragma unroll
      for (int e = 0; e < 4; ++e) {
        int prow = lg*4 + e;
        float rs = 0.f;
        #pragma unroll
        for (int ct = 0; ct < 4; ++ct) {
          float pv = (sv[e][ct] > -1e29f) ? __expf(sv[e][ct] - m_run[e]) : 0.f;
          rs += pv;
          Ps_w[prow*64 + ((ct*2 + (lr >> 3)) ^ (prow & 7))*8 + (lr & 7)] = f2bf(pv);
        }
        #pragma unroll
        for (int msk = 1; msk < 16; msk <<= 1) rs += __shfl_xor(rs, msk);
        l_sum[e] += rs;
      }
      asm volatile("s_waitcnt lgkmcnt(0)" ::: "memory"); SB();
      #pragma unroll
      for (int kk = 0; kk < 2; ++kk) {
        bf16x8 pf = *(const bf16x8*)&Ps_w[lr*64 + ((kk*4 + lg) ^ (lr & 7))*8];
        #pragma unroll
        for (int nt = 0; nt < 8; ++nt) {
          bf16x8 vf = *(const bf16x8*)&Vs[(nt*16 + lr)*64 + ((kk*4 + lg) ^ (lr & 7))*8];
          o[nt] = __builtin_amdgcn_mfma_f32_16x16x32_bf16(pf, vf, o[nt], 0, 0, 0);
        }
      }
    }
    asm volatile("s_waitcnt lgkmcnt(0)" ::: "memory");
    __builtin_amdgcn_s_barrier();
    cur ^= 1;
  }

  #pragma unroll
  for (int nt = 0; nt < 8; ++nt) {
    #pragma unroll
    for (int e = 0; e < 4; ++e) {
      int t = q0 + wv*16 + lg*4 + e;
      int d = nt*16 + lr;
      y[(size_t)(b*T_ + t) * C_ + h*D_ + d] = f2bf(o[nt][e] / l_sum[e]);
    }
  }
}

extern "C" void kernel_launch(void* const* d_in, const int* in_sizes, int n_in,
                              void* d_out, int out_size, void* d_ws, size_t ws_size,
                              hipStream_t stream) {
  const float* x      = (const float*)d_in[0];
  const float* fcos   = (const float*)d_in[1];
  const float* fsin   = (const float*)d_in[2];
  const float* w_attn = (const float*)d_in[3];
  const float* w_proj = (const float*)d_in[4];
  float* out = (float*)d_out;

  char* ws = (char*)d_ws;
  unsigned short* x_bf = (unsigned short*)(ws);
  unsigned short* wa_t = (unsigned short*)(ws + 16777216ull);
  unsigned short* wp_t = (unsigned short*)(ws + 41943040ull);
  unsigned short* vq   = (unsigned short*)(ws + 50331648ull);
  unsigned short* q_r  = (unsigned short*)(ws + 100663296ull);
  unsigned short* k_r  = (unsigned short*)(ws + 117440512ull);
  unsigned short* v_t  = (unsigned short*)(ws + 134217728ull);
  unsigned short* y_bf = x_bf;

  k_cvt<<<dim3(4096), dim3(256), 0, stream>>>(x, x_bf, M_*C_);
  k_tcvt<<<dim3(192, 64), dim3(256), 0, stream>>>(w_attn, wa_t, C_, N1_);
  k_tcvt<<<dim3(64, 64), dim3(256), 0, stream>>>(w_proj, wp_t, C_, C_);
  k_gemmF<C_, N1_><<<dim3(384), dim3(512), 0, stream>>>(x_bf, wa_t, fcos, fsin, q_r, k_r, vq);
  k_vt<<<dim3(32, 32), dim3(256), 0, stream>>>(vq, v_t);
  k_attn<<<dim3(32, 8), dim3(1024), 0, stream>>>(q_r, k_r, v_t, y_bf);
  k_gemmS<C_, C_><<<dim3(512), dim3(512), 0, stream>>>(y_bf, wp_t, out);
}

// Round 19
// 248.165 us; speedup vs baseline: 1.0238x; 1.0238x over previous
//
#include <hip/hip_runtime.h>
#include <stdint.h>

#define B_ 2
#define T_ 2048
#define C_ 2048
#define H_ 16
#define D_ 128
#define W_ 512
#define M_ (B_*T_)      // 4096
#define N1_ (3*C_)      // 6144

typedef short bf16x8 __attribute__((ext_vector_type(8)));
typedef unsigned short u16x8 __attribute__((ext_vector_type(8)));
typedef unsigned short u16x4 __attribute__((ext_vector_type(4)));
typedef float f32x4 __attribute__((ext_vector_type(4)));

#define SB() __builtin_amdgcn_sched_barrier(0)

__device__ __forceinline__ unsigned short f2bf(float f) {
  union { float f; unsigned u; } v; v.f = f;
  unsigned r = v.u + 0x7fffu + ((v.u >> 16) & 1u);
  return (unsigned short)(r >> 16);
}
__device__ __forceinline__ float bf2f(unsigned short b) {
  union { unsigned u; float f; } v; v.u = ((unsigned)b) << 16;
  return v.f;
}

__device__ __forceinline__ void gload_lds16(const void* g, void* l) {
  __builtin_amdgcn_global_load_lds((const __attribute__((address_space(1))) void*)g,
                                   (__attribute__((address_space(3))) void*)l, 16, 0, 0);
}

// ---------- fp32 -> bf16 convert ----------
__global__ void k_cvt(const float* __restrict__ s, unsigned short* __restrict__ d, int n) {
  int i = (blockIdx.x * blockDim.x + threadIdx.x) * 8;
  if (i >= n) return;
  float4 a = *(const float4*)(s + i);
  float4 b = *(const float4*)(s + i + 4);
  u16x8 o;
  o[0]=f2bf(a.x); o[1]=f2bf(a.y); o[2]=f2bf(a.z); o[3]=f2bf(a.w);
  o[4]=f2bf(b.x); o[5]=f2bf(b.y); o[6]=f2bf(b.z); o[7]=f2bf(b.w);
  *(u16x8*)(d + i) = o;
}

// ---------- transpose + convert: src [R][Cc] f32 -> dst [Cc][R] bf16 ----------
__global__ void k_tcvt(const float* __restrict__ s, unsigned short* __restrict__ d, int R, int Cc) {
  __shared__ float tile[32][33];
  int c0 = blockIdx.x * 32, r0 = blockIdx.y * 32;
  int tx = threadIdx.x & 31, ty = threadIdx.x >> 5;
  #pragma unroll
  for (int j = 0; j < 32; j += 8) tile[ty + j][tx] = s[(size_t)(r0 + ty + j) * Cc + c0 + tx];
  __syncthreads();
  #pragma unroll
  for (int j = 0; j < 32; j += 8) d[(size_t)(c0 + ty + j) * R + r0 + tx] = f2bf(tile[tx][ty + j]);
}

// ---------- staging helper (512-thread blocks): st_16x32 XOR swizzle ----------
template<int ROWS, int K>
__device__ __forceinline__ void stage_half(const unsigned short* __restrict__ gbase,
                                           int row0, int kt, int kh,
                                           unsigned short* region, int tid, int sw) {
  const char* gsrc = (const char*)(gbase + (size_t)row0 * K + kt * 64 + kh * 32);
  {
    int o = tid * 16, s = o ^ sw;
    gload_lds16(gsrc + (size_t)(s >> 6) * (K * 2) + (s & 63), (char*)region + o);
  }
  if (ROWS == 256) {
    int o = (512 + tid) * 16, s = o ^ sw;
    gload_lds16(gsrc + (size_t)(s >> 6) * (K * 2) + (s & 63), (char*)region + o);
  }
}

// ---------- GEMM1 fused: 256x256 4-phase + RoPE epilogue + direct v_t -------
template<int K, int Ntot>
__global__ __launch_bounds__(512, 2) void k_gemmF(const unsigned short* __restrict__ A,
                                                  const unsigned short* __restrict__ Bt,
                                                  const float* __restrict__ fcos,
                                                  const float* __restrict__ fsin,
                                                  unsigned short* __restrict__ q_r,
                                                  unsigned short* __restrict__ k_r,
                                                  unsigned short* __restrict__ v_t) {
  __shared__ unsigned short As[2][2][256 * 32];
  __shared__ unsigned short Bs[2][2][256 * 32];
  const int tid = threadIdx.x, lane = tid & 63, wv = tid >> 6;
  const int wm = wv >> 2, wn = wv & 3;
  const int lr = lane & 15, lg = lane >> 4;
  const int sw = tid & 32;
  const int fofs = lr * 64 + ((lg * 16) ^ ((lr & 8) << 2));
  const int aoff = wm * 128 * 64 + fofs;
  int bofs[4];
  #pragma unroll
  for (int j = 0; j < 4; ++j)
    bofs[j] = ((wn >> 1) * 128 + (wn & 1) * 32 + (j >> 1) * 64 + (j & 1) * 16) * 64 + fofs;

  const int nwg = gridDim.x;
  const int nbx = Ntot >> 8;
  const int q = nwg >> 3, r = nwg & 7;
  const int xcd = blockIdx.x & 7, off = blockIdx.x >> 3;
  const int bid = (xcd < r ? xcd * (q + 1) : r * (q + 1) + (xcd - r) * q) + off;
  const int bm0 = (bid / nbx) << 8;
  const int bn0 = (bid % nbx) << 8;

  f32x4 acc[8][4];
  #pragma unroll
  for (int i = 0; i < 8; ++i)
    #pragma unroll
    for (int j = 0; j < 4; ++j)
      #pragma unroll
      for (int e = 0; e < 4; ++e) acc[i][j][e] = 0.f;

  constexpr int NT = K >> 6;

  stage_half<256, K>(A,  bm0, 0, 0, As[0][0], tid, sw);
  stage_half<256, K>(Bt, bn0, 0, 0, Bs[0][0], tid, sw);
  stage_half<256, K>(Bt, bn0, 0, 1, Bs[0][1], tid, sw);
  stage_half<256, K>(A,  bm0, 0, 1, As[0][1], tid, sw);
  stage_half<256, K>(Bt, bn0, 1, 0, Bs[1][0], tid, sw);
  stage_half<256, K>(A,  bm0, 1, 0, As[1][0], tid, sw);
  stage_half<256, K>(Bt, bn0, 1, 1, Bs[1][1], tid, sw);
  asm volatile("s_waitcnt vmcnt(4)" ::: "memory");
  __builtin_amdgcn_s_barrier();

  bf16x8 Xa[4], Xb[4], Ya[4];
  #pragma unroll
  for (int j = 0; j < 4; ++j) Xb[j] = *(const bf16x8*)((const char*)Bs[0][0] + bofs[j]);
  #pragma unroll
  for (int i = 0; i < 4; ++i) Xa[i] = *(const bf16x8*)((const char*)As[0][0] + aoff + i * 1024);

  #pragma unroll 2
  for (int t = 0; t < NT; ++t) {
    const int p = t & 1;
    // ---- ph0 ----
    asm volatile("s_waitcnt lgkmcnt(0)" ::: "memory");
    SB();
    __builtin_amdgcn_s_setprio(1);
    #pragma unroll
    for (int i = 0; i < 4; ++i)
      #pragma unroll
      for (int j = 0; j < 4; ++j)
        acc[i][j] = __builtin_amdgcn_mfma_f32_16x16x32_bf16(Xa[i], Xb[j], acc[i][j], 0, 0, 0);
    __builtin_amdgcn_s_setprio(0);
    #pragma unroll
    for (int i = 0; i < 4; ++i) Ya[i] = *(const bf16x8*)((const char*)As[p][0] + aoff + (i + 4) * 1024);
    if (t + 1 < NT) stage_half<256, K>(A, bm0, t + 1, 1, As[p ^ 1][1], tid, sw);
    __builtin_amdgcn_s_barrier();

    // ---- ph1 ----
    asm volatile("s_waitcnt lgkmcnt(0)" ::: "memory");
    SB();
    __builtin_amdgcn_s_setprio(1);
    #pragma unroll
    for (int i = 0; i < 4; ++i)
      #pragma unroll
      for (int j = 0; j < 4; ++j)
        acc[i + 4][j] = __builtin_amdgcn_mfma_f32_16x16x32_bf16(Ya[i], Xb[j], acc[i + 4][j], 0, 0, 0);
    __builtin_amdgcn_s_setprio(0);
    #pragma unroll
    for (int j = 0; j < 4; ++j) Xb[j] = *(const bf16x8*)((const char*)Bs[p][1] + bofs[j]);
    #pragma unroll
    for (int i = 0; i < 4; ++i) Xa[i] = *(const bf16x8*)((const char*)As[p][1] + aoff + i * 1024);
    if (t + 2 < NT) stage_half<256, K>(Bt, bn0, t + 2, 0, Bs[p][0], tid, sw);
    __builtin_amdgcn_s_barrier();

    // ---- ph2 ----
    asm volatile("s_waitcnt lgkmcnt(0)" ::: "memory");
    SB();
    __builtin_amdgcn_s_setprio(1);
    #pragma unroll
    for (int i = 0; i < 4; ++i)
      #pragma unroll
      for (int j = 0; j < 4; ++j)
        acc[i][j] = __builtin_amdgcn_mfma_f32_16x16x32_bf16(Xa[i], Xb[j], acc[i][j], 0, 0, 0);
    __builtin_amdgcn_s_setprio(0);
    #pragma unroll
    for (int i = 0; i < 4; ++i) Ya[i] = *(const bf16x8*)((const char*)As[p][1] + aoff + (i + 4) * 1024);
    if (t + 2 < NT) stage_half<256, K>(A, bm0, t + 2, 0, As[p][0], tid, sw);
    __builtin_amdgcn_s_barrier();

    // ---- ph3 ----
    asm volatile("s_waitcnt lgkmcnt(0)" ::: "memory");
    SB();
    __builtin_amdgcn_s_setprio(1);
    #pragma unroll
    for (int i = 0; i < 4; ++i)
      #pragma unroll
      for (int j = 0; j < 4; ++j)
        acc[i + 4][j] = __builtin_amdgcn_mfma_f32_16x16x32_bf16(Ya[i], Xb[j], acc[i + 4][j], 0, 0, 0);
    __builtin_amdgcn_s_setprio(0);
    if (t < NT - 2) asm volatile("s_waitcnt vmcnt(4)" ::: "memory");
    else            asm volatile("s_waitcnt vmcnt(0)" ::: "memory");
    #pragma unroll
    for (int j = 0; j < 4; ++j) Xb[j] = *(const bf16x8*)((const char*)Bs[p ^ 1][0] + bofs[j]);
    #pragma unroll
    for (int i = 0; i < 4; ++i) Xa[i] = *(const bf16x8*)((const char*)As[p ^ 1][0] + aoff + i * 1024);
    if (t + 2 < NT) stage_half<256, K>(Bt, bn0, t + 2, 1, Bs[p][1], tid, sw);
    __builtin_amdgcn_s_barrier();
  }
  asm volatile("s_waitcnt lgkmcnt(0)" ::: "memory");

  // ---------- fused epilogue ----------
  const int nb  = bn0 >> 11;        // 0=q, 1=k, 2=v
  const int rem = bn0 & 2047;
  const int b   = bm0 >> 11;
  const int t0  = bm0 & 2047;
  const int wcb = (wn >> 1) * 128 + (wn & 1) * 32;

  if (nb == 2) {
    // v: write v_t (b,h,d,t) directly — e spans 4 consecutive t (8B store)
    #pragma unroll
    for (int i = 0; i < 8; ++i)
      #pragma unroll
      for (int j = 0; j < 4; ++j) {
        int col = rem + wcb + (j >> 1) * 64 + (j & 1) * 16 + lr;
        int head = col >> 7, d = col & 127;
        int tb = t0 + wm * 128 + i * 16 + lg * 4;
        u16x4 st;
        #pragma unroll
        for (int e = 0; e < 4; ++e) st[e] = f2bf(acc[i][j][e]);
        *(u16x4*)(v_t + ((size_t)(b * H_ + head) * D_ + d) * T_ + tb) = st;
      }
  } else {
    unsigned short* dst = nb ? k_r : q_r;
    #pragma unroll
    for (int i = 0; i < 8; ++i)
      #pragma unroll
      for (int j = 0; j < 4; ++j) {
        int col = rem + wcb + (j >> 1) * 64 + (j & 1) * 16 + lr;
        int head = col >> 7, d = col & 127;
        float sgn = (j < 2) ? -1.f : 1.f;
        #pragma unroll
        for (int e = 0; e < 4; ++e) {
          int t = t0 + wm * 128 + i * 16 + lg * 4 + e;
          float c = fcos[t * D_ + d];
          float s = fsin[t * D_ + d];
          float out = acc[i][j][e] * c + sgn * acc[i][j ^ 2][e] * s;
          dst[((size_t)(b * H_ + head) * T_ + t) * D_ + d] = f2bf(out);
        }
      }
  }
}

// ---------- GEMM2: 128x128 tile, 8 waves, dbuf, 2 blocks/CU (R14) ----------
template<int K, int Ntot>
__global__ __launch_bounds__(512, 4) void k_gemmS(const unsigned short* __restrict__ A,
                                                  const unsigned short* __restrict__ Bt,
                                                  float* __restrict__ Cp) {
  __shared__ unsigned short As[2][2][128 * 32];
  __shared__ unsigned short Bs[2][2][128 * 32];
  const int tid = threadIdx.x, lane = tid & 63, wv = tid >> 6;
  const int wm = wv >> 1, wn = wv & 1;
  const int lr = lane & 15, lg = lane >> 4;
  const int sw = tid & 32;
  const int fofs = lr * 64 + ((lg * 16) ^ ((lr & 8) << 2));
  const int aoff = wm * 32 * 64 + fofs;
  const int boff = wn * 64 * 64 + fofs;

  const int nwg = gridDim.x;
  const int nbx = Ntot >> 7;
  const int q = nwg >> 3, r = nwg & 7;
  const int xcd = blockIdx.x & 7, off = blockIdx.x >> 3;
  const int bid = (xcd < r ? xcd * (q + 1) : r * (q + 1) + (xcd - r) * q) + off;
  const int bm0 = (bid / nbx) << 7;
  const int bn0 = (bid % nbx) << 7;

  f32x4 acc[2][4];
  #pragma unroll
  for (int i = 0; i < 2; ++i)
    #pragma unroll
    for (int j = 0; j < 4; ++j)
      #pragma unroll
      for (int e = 0; e < 4; ++e) acc[i][j][e] = 0.f;

  constexpr int NT = K >> 6;

  auto stage_tile = [&](int kt, int rr) {
    stage_half<128, K>(A,  bm0, kt, 0, As[rr][0], tid, sw);
    stage_half<128, K>(Bt, bn0, kt, 0, Bs[rr][0], tid, sw);
    stage_half<128, K>(A,  bm0, kt, 1, As[rr][1], tid, sw);
    stage_half<128, K>(Bt, bn0, kt, 1, Bs[rr][1], tid, sw);
  };

  stage_tile(0, 0);
  asm volatile("s_waitcnt vmcnt(0)" ::: "memory");
  __builtin_amdgcn_s_barrier();

  for (int t = 0; t < NT; ++t) {
    const int p = t & 1;
    if (t + 1 < NT) stage_tile(t + 1, p ^ 1);

    bf16x8 af[2], bfr[4];
    #pragma unroll
    for (int kh = 0; kh < 2; ++kh) {
      #pragma unroll
      for (int i = 0; i < 2; ++i) af[i] = *(const bf16x8*)((const char*)As[p][kh] + aoff + i * 1024);
      #pragma unroll
      for (int j = 0; j < 4; ++j) bfr[j] = *(const bf16x8*)((const char*)Bs[p][kh] + boff + j * 1024);
      asm volatile("s_waitcnt lgkmcnt(0)" ::: "memory");
      SB();
      __builtin_amdgcn_s_setprio(1);
      #pragma unroll
      for (int i = 0; i < 2; ++i)
        #pragma unroll
        for (int j = 0; j < 4; ++j)
          acc[i][j] = __builtin_amdgcn_mfma_f32_16x16x32_bf16(af[i], bfr[j], acc[i][j], 0, 0, 0);
      __builtin_amdgcn_s_setprio(0);
    }
    asm volatile("s_waitcnt vmcnt(0)" ::: "memory");
    __builtin_amdgcn_s_barrier();
  }

  #pragma unroll
  for (int i = 0; i < 2; ++i)
    #pragma unroll
    for (int j = 0; j < 4; ++j) {
      int m = bm0 + wm * 32 + i * 16 + lg * 4;
      int n = bn0 + wn * 64 + j * 16 + lr;
      #pragma unroll
      for (int e = 0; e < 4; ++e)
        Cp[(size_t)(m + e) * Ntot + n] = acc[i][j][e];
    }
}

// ---------- attention: 8 waves, q=128/block, 2 barriers/tile (R17 best) -----
__global__ __launch_bounds__(512, 4) void k_attn(const unsigned short* __restrict__ q_r,
                       const unsigned short* __restrict__ k_r,
                       const unsigned short* __restrict__ v_t,
                       unsigned short* __restrict__ y) {
  const int bh = blockIdx.x, b = bh >> 4, h = bh & 15;
  const int q0 = blockIdx.y * 128;
  const int tid = threadIdx.x, lane = tid & 63, wv = tid >> 6;
  const int lr = lane & 15, lg = lane >> 4;

  __shared__ unsigned short Ks[2][64 * 128];
  __shared__ unsigned short Vs[128 * 64];
  __shared__ unsigned short Ps[8 * 16 * 64];

  const size_t bhT = (size_t)(b*H_ + h) * T_;
  const size_t bhD = (size_t)(b*H_ + h) * D_;
  const unsigned short* qbase = q_r + (bhT + q0 + wv*16 + lr) * D_;
  bf16x8 qf[4];
  #pragma unroll
  for (int kk = 0; kk < 4; ++kk) qf[kk] = *(const bf16x8*)(qbase + kk*32 + lg*8);

  f32x4 o[8];
  #pragma unroll
  for (int i = 0; i < 8; ++i)
    #pragma unroll
    for (int e = 0; e < 4; ++e) o[i][e] = 0.f;
  float m_run[4], l_sum[4];
  #pragma unroll
  for (int e = 0; e < 4; ++e) { m_run[e] = -1e30f; l_sum[e] = 0.f; }

  const int i_min = q0 + wv*16, i_max = i_min + 15;
  int kt_lo = q0 - (W_ - 1); if (kt_lo < 0) kt_lo = 0; kt_lo &= ~63;
  const float scale = 0.08838834764831845f;

  unsigned short* Ps_w = Ps + wv * 1024;

  auto stage_k = [&](int kt, int buf) {
    #pragma unroll
    for (int c = 0; c < 2; ++c) {
      int ob = (c * 512 + tid) * 16;
      int row = ob >> 8, slot = (ob >> 4) & 15;
      int cb = slot ^ ((row & 7) << 1);
      gload_lds16(k_r + (bhT + kt + row) * D_ + cb * 8, (char*)Ks[buf] + ob);
    }
  };
  auto stage_v = [&](int kt) {
    #pragma unroll
    for (int c = 0; c < 2; ++c) {
      int ob = (c * 512 + tid) * 16;
      int d = ob >> 7, slot = (ob >> 4) & 7;
      int cb = slot ^ (d & 7);
      gload_lds16(v_t + (bhD + d) * T_ + kt + cb * 8, (char*)Vs + ob);
    }
  };

  stage_k(kt_lo, 0);
  int cur = 0;
  for (int kt = kt_lo; kt < q0 + 128; kt += 64) {
    const bool has_next = (kt + 64 < q0 + 128);
    stage_v(kt);
    if (has_next) stage_k(kt + 64, cur ^ 1);
    if (has_next) asm volatile("s_waitcnt vmcnt(2)" ::: "memory");
    else          asm volatile("s_waitcnt vmcnt(0)" ::: "memory");
    __builtin_amdgcn_s_barrier();

    const bool live = (kt <= i_max) && (kt + 63 >= i_min - (W_ - 1));
    float sv[4][4];
    if (live) {
      const unsigned short* Kc = Ks[cur];
      f32x4 s[4];
      #pragma unroll
      for (int ct = 0; ct < 4; ++ct)
        #pragma unroll
        for (int e = 0; e < 4; ++e) s[ct][e] = 0.f;
      #pragma unroll
      for (int kk = 0; kk < 4; ++kk) {
        #pragma unroll
        for (int ct = 0; ct < 4; ++ct) {
          bf16x8 kf = *(const bf16x8*)&Kc[(ct*16 + lr)*128 + ((kk*4 + lg) ^ ((lr & 7) << 1))*8];
          s[ct] = __builtin_amdgcn_mfma_f32_16x16x32_bf16(qf[kk], kf, s[ct], 0, 0, 0);
        }
      }
      float mnew[4];
      int grow = 0;
      #pragma unroll
      for (int e = 0; e < 4; ++e) {
        int i = i_min + lg*4 + e;
        float rm = -1e30f;
        #pragma unroll
        for (int ct = 0; ct < 4; ++ct) {
          int j = kt + ct*16 + lr;
          bool ok = (j <= i) && (j > i - W_);
          sv[e][ct] = ok ? s[ct][e] * scale : -1e30f;
          rm = fmaxf(rm, sv[e][ct]);
        }
        #pragma unroll
        for (int msk = 1; msk < 16; msk <<= 1) rm = fmaxf(rm, __shfl_xor(rm, msk));
        mnew[e] = fmaxf(m_run[e], rm);
        grow |= (mnew[e] > m_run[e]) ? 1 : 0;
      }
      if (__any(grow)) {
        #pragma unroll
        for (int e = 0; e < 4; ++e) {
          float fac = __expf(m_run[e] - mnew[e]);
          l_sum[e] *= fac;
          m_run[e] = mnew[e];
          #pragma unroll
          for (int nt = 0; nt < 8; ++nt) o[nt][e] *= fac;
        }
      }
      #pragma unroll
      for (int e = 0; e < 4; ++e) {
        int prow = lg*4 + e;
        float rs = 0.f;
        #pragma unroll
        for (int ct = 0; ct < 4; ++ct) {
          float pv = (sv[e][ct] > -1e29f) ? __expf(sv[e][ct] - m_run[e]) : 0.f;
          rs += pv;
          Ps_w[prow*64 + ((ct*2 + (lr >> 3)) ^ (prow & 7))*8 + (lr & 7)] = f2bf(pv);
        }
        #pragma unroll
        for (int msk = 1; msk < 16; msk <<= 1) rs += __shfl_xor(rs, msk);
        l_sum[e] += rs;
      }
      asm volatile("s_waitcnt lgkmcnt(0)" ::: "memory"); SB();
      #pragma unroll
      for (int kk = 0; kk < 2; ++kk) {
        bf16x8 pf = *(const bf16x8*)&Ps_w[lr*64 + ((kk*4 + lg) ^ (lr & 7))*8];
        #pragma unroll
        for (int nt = 0; nt < 8; ++nt) {
          bf16x8 vf = *(const bf16x8*)&Vs[(nt*16 + lr)*64 + ((kk*4 + lg) ^ (lr & 7))*8];
          o[nt] = __builtin_amdgcn_mfma_f32_16x16x32_bf16(pf, vf, o[nt], 0, 0, 0);
        }
      }
    }
    asm volatile("s_waitcnt lgkmcnt(0)" ::: "memory");
    __builtin_amdgcn_s_barrier();
    cur ^= 1;
  }

  #pragma unroll
  for (int nt = 0; nt < 8; ++nt) {
    #pragma unroll
    for (int e = 0; e < 4; ++e) {
      int t = q0 + wv*16 + lg*4 + e;
      int d = nt*16 + lr;
      y[(size_t)(b*T_ + t) * C_ + h*D_ + d] = f2bf(o[nt][e] / l_sum[e]);
    }
  }
}

extern "C" void kernel_launch(void* const* d_in, const int* in_sizes, int n_in,
                              void* d_out, int out_size, void* d_ws, size_t ws_size,
                              hipStream_t stream) {
  const float* x      = (const float*)d_in[0];
  const float* fcos   = (const float*)d_in[1];
  const float* fsin   = (const float*)d_in[2];
  const float* w_attn = (const float*)d_in[3];
  const float* w_proj = (const float*)d_in[4];
  float* out = (float*)d_out;

  char* ws = (char*)d_ws;
  unsigned short* x_bf = (unsigned short*)(ws);
  unsigned short* wa_t = (unsigned short*)(ws + 16777216ull);
  unsigned short* wp_t = (unsigned short*)(ws + 41943040ull);
  unsigned short* q_r  = (unsigned short*)(ws + 100663296ull);
  unsigned short* k_r  = (unsigned short*)(ws + 117440512ull);
  unsigned short* v_t  = (unsigned short*)(ws + 134217728ull);
  unsigned short* y_bf = x_bf;

  k_cvt<<<dim3(4096), dim3(256), 0, stream>>>(x, x_bf, M_*C_);
  k_tcvt<<<dim3(192, 64), dim3(256), 0, stream>>>(w_attn, wa_t, C_, N1_);
  k_tcvt<<<dim3(64, 64), dim3(256), 0, stream>>>(w_proj, wp_t, C_, C_);
  k_gemmF<C_, N1_><<<dim3(384), dim3(512), 0, stream>>>(x_bf, wa_t, fcos, fsin, q_r, k_r, v_t);
  k_attn<<<dim3(32, 16), dim3(512), 0, stream>>>(q_r, k_r, v_t, y_bf);
  k_gemmS<C_, C_><<<dim3(512), dim3(512), 0, stream>>>(y_bf, wp_t, out);
}

// Round 20
// 248.164 us; speedup vs baseline: 1.0238x; 1.0000x over previous
//
#include <hip/hip_runtime.h>
#include <stdint.h>

#define B_ 2
#define T_ 2048
#define C_ 2048
#define H_ 16
#define D_ 128
#define W_ 512
#define M_ (B_*T_)      // 4096
#define N1_ (3*C_)      // 6144

typedef short bf16x8 __attribute__((ext_vector_type(8)));
typedef unsigned short u16x8 __attribute__((ext_vector_type(8)));
typedef unsigned short u16x4 __attribute__((ext_vector_type(4)));
typedef float f32x4 __attribute__((ext_vector_type(4)));

#define SB() __builtin_amdgcn_sched_barrier(0)

__device__ __forceinline__ unsigned short f2bf(float f) {
  union { float f; unsigned u; } v; v.f = f;
  unsigned r = v.u + 0x7fffu + ((v.u >> 16) & 1u);
  return (unsigned short)(r >> 16);
}
__device__ __forceinline__ float bf2f(unsigned short b) {
  union { unsigned u; float f; } v; v.u = ((unsigned)b) << 16;
  return v.f;
}

__device__ __forceinline__ void gload_lds16(const void* g, void* l) {
  __builtin_amdgcn_global_load_lds((const __attribute__((address_space(1))) void*)g,
                                   (__attribute__((address_space(3))) void*)l, 16, 0, 0);
}

// ---------- fp32 -> bf16 convert ----------
__global__ void k_cvt(const float* __restrict__ s, unsigned short* __restrict__ d, int n) {
  int i = (blockIdx.x * blockDim.x + threadIdx.x) * 8;
  if (i >= n) return;
  float4 a = *(const float4*)(s + i);
  float4 b = *(const float4*)(s + i + 4);
  u16x8 o;
  o[0]=f2bf(a.x); o[1]=f2bf(a.y); o[2]=f2bf(a.z); o[3]=f2bf(a.w);
  o[4]=f2bf(b.x); o[5]=f2bf(b.y); o[6]=f2bf(b.z); o[7]=f2bf(b.w);
  *(u16x8*)(d + i) = o;
}

// ---------- transpose + convert: src [R][Cc] f32 -> dst [Cc][R] bf16 ----------
__global__ void k_tcvt(const float* __restrict__ s, unsigned short* __restrict__ d, int R, int Cc) {
  __shared__ float tile[32][33];
  int c0 = blockIdx.x * 32, r0 = blockIdx.y * 32;
  int tx = threadIdx.x & 31, ty = threadIdx.x >> 5;
  #pragma unroll
  for (int j = 0; j < 32; j += 8) tile[ty + j][tx] = s[(size_t)(r0 + ty + j) * Cc + c0 + tx];
  __syncthreads();
  #pragma unroll
  for (int j = 0; j < 32; j += 8) d[(size_t)(c0 + ty + j) * R + r0 + tx] = f2bf(tile[tx][ty + j]);
}

// ---------- staging helper (512-thread blocks): st_16x32 XOR swizzle ----------
template<int ROWS, int K>
__device__ __forceinline__ void stage_half(const unsigned short* __restrict__ gbase,
                                           int row0, int kt, int kh,
                                           unsigned short* region, int tid, int sw) {
  const char* gsrc = (const char*)(gbase + (size_t)row0 * K + kt * 64 + kh * 32);
  {
    int o = tid * 16, s = o ^ sw;
    gload_lds16(gsrc + (size_t)(s >> 6) * (K * 2) + (s & 63), (char*)region + o);
  }
  if (ROWS == 256) {
    int o = (512 + tid) * 16, s = o ^ sw;
    gload_lds16(gsrc + (size_t)(s >> 6) * (K * 2) + (s & 63), (char*)region + o);
  }
}

// ---------- GEMM1 fused: 256x256 4-phase + RoPE epilogue + direct v_t -------
template<int K, int Ntot>
__global__ __launch_bounds__(512, 2) void k_gemmF(const unsigned short* __restrict__ A,
                                                  const unsigned short* __restrict__ Bt,
                                                  const float* __restrict__ fcos,
                                                  const float* __restrict__ fsin,
                                                  unsigned short* __restrict__ q_r,
                                                  unsigned short* __restrict__ k_r,
                                                  unsigned short* __restrict__ v_t) {
  __shared__ unsigned short As[2][2][256 * 32];
  __shared__ unsigned short Bs[2][2][256 * 32];
  const int tid = threadIdx.x, lane = tid & 63, wv = tid >> 6;
  const int wm = wv >> 2, wn = wv & 3;
  const int lr = lane & 15, lg = lane >> 4;
  const int sw = tid & 32;
  const int fofs = lr * 64 + ((lg * 16) ^ ((lr & 8) << 2));
  const int aoff = wm * 128 * 64 + fofs;
  int bofs[4];
  #pragma unroll
  for (int j = 0; j < 4; ++j)
    bofs[j] = ((wn >> 1) * 128 + (wn & 1) * 32 + (j >> 1) * 64 + (j & 1) * 16) * 64 + fofs;

  const int nwg = gridDim.x;
  const int nbx = Ntot >> 8;
  const int q = nwg >> 3, r = nwg & 7;
  const int xcd = blockIdx.x & 7, off = blockIdx.x >> 3;
  const int bid = (xcd < r ? xcd * (q + 1) : r * (q + 1) + (xcd - r) * q) + off;
  const int bm0 = (bid / nbx) << 8;
  const int bn0 = (bid % nbx) << 8;

  f32x4 acc[8][4];
  #pragma unroll
  for (int i = 0; i < 8; ++i)
    #pragma unroll
    for (int j = 0; j < 4; ++j)
      #pragma unroll
      for (int e = 0; e < 4; ++e) acc[i][j][e] = 0.f;

  constexpr int NT = K >> 6;

  stage_half<256, K>(A,  bm0, 0, 0, As[0][0], tid, sw);
  stage_half<256, K>(Bt, bn0, 0, 0, Bs[0][0], tid, sw);
  stage_half<256, K>(Bt, bn0, 0, 1, Bs[0][1], tid, sw);
  stage_half<256, K>(A,  bm0, 0, 1, As[0][1], tid, sw);
  stage_half<256, K>(Bt, bn0, 1, 0, Bs[1][0], tid, sw);
  stage_half<256, K>(A,  bm0, 1, 0, As[1][0], tid, sw);
  stage_half<256, K>(Bt, bn0, 1, 1, Bs[1][1], tid, sw);
  asm volatile("s_waitcnt vmcnt(4)" ::: "memory");
  __builtin_amdgcn_s_barrier();

  bf16x8 Xa[4], Xb[4], Ya[4];
  #pragma unroll
  for (int j = 0; j < 4; ++j) Xb[j] = *(const bf16x8*)((const char*)Bs[0][0] + bofs[j]);
  #pragma unroll
  for (int i = 0; i < 4; ++i) Xa[i] = *(const bf16x8*)((const char*)As[0][0] + aoff + i * 1024);

  #pragma unroll 2
  for (int t = 0; t < NT; ++t) {
    const int p = t & 1;
    // ---- ph0 ----
    asm volatile("s_waitcnt lgkmcnt(0)" ::: "memory");
    SB();
    __builtin_amdgcn_s_setprio(1);
    #pragma unroll
    for (int i = 0; i < 4; ++i)
      #pragma unroll
      for (int j = 0; j < 4; ++j)
        acc[i][j] = __builtin_amdgcn_mfma_f32_16x16x32_bf16(Xa[i], Xb[j], acc[i][j], 0, 0, 0);
    __builtin_amdgcn_s_setprio(0);
    #pragma unroll
    for (int i = 0; i < 4; ++i) Ya[i] = *(const bf16x8*)((const char*)As[p][0] + aoff + (i + 4) * 1024);
    if (t + 1 < NT) stage_half<256, K>(A, bm0, t + 1, 1, As[p ^ 1][1], tid, sw);
    __builtin_amdgcn_s_barrier();

    // ---- ph1 ----
    asm volatile("s_waitcnt lgkmcnt(0)" ::: "memory");
    SB();
    __builtin_amdgcn_s_setprio(1);
    #pragma unroll
    for (int i = 0; i < 4; ++i)
      #pragma unroll
      for (int j = 0; j < 4; ++j)
        acc[i + 4][j] = __builtin_amdgcn_mfma_f32_16x16x32_bf16(Ya[i], Xb[j], acc[i + 4][j], 0, 0, 0);
    __builtin_amdgcn_s_setprio(0);
    #pragma unroll
    for (int j = 0; j < 4; ++j) Xb[j] = *(const bf16x8*)((const char*)Bs[p][1] + bofs[j]);
    #pragma unroll
    for (int i = 0; i < 4; ++i) Xa[i] = *(const bf16x8*)((const char*)As[p][1] + aoff + i * 1024);
    if (t + 2 < NT) stage_half<256, K>(Bt, bn0, t + 2, 0, Bs[p][0], tid, sw);
    __builtin_amdgcn_s_barrier();

    // ---- ph2 ----
    asm volatile("s_waitcnt lgkmcnt(0)" ::: "memory");
    SB();
    __builtin_amdgcn_s_setprio(1);
    #pragma unroll
    for (int i = 0; i < 4; ++i)
      #pragma unroll
      for (int j = 0; j < 4; ++j)
        acc[i][j] = __builtin_amdgcn_mfma_f32_16x16x32_bf16(Xa[i], Xb[j], acc[i][j], 0, 0, 0);
    __builtin_amdgcn_s_setprio(0);
    #pragma unroll
    for (int i = 0; i < 4; ++i) Ya[i] = *(const bf16x8*)((const char*)As[p][1] + aoff + (i + 4) * 1024);
    if (t + 2 < NT) stage_half<256, K>(A, bm0, t + 2, 0, As[p][0], tid, sw);
    __builtin_amdgcn_s_barrier();

    // ---- ph3 ----
    asm volatile("s_waitcnt lgkmcnt(0)" ::: "memory");
    SB();
    __builtin_amdgcn_s_setprio(1);
    #pragma unroll
    for (int i = 0; i < 4; ++i)
      #pragma unroll
      for (int j = 0; j < 4; ++j)
        acc[i + 4][j] = __builtin_amdgcn_mfma_f32_16x16x32_bf16(Ya[i], Xb[j], acc[i + 4][j], 0, 0, 0);
    __builtin_amdgcn_s_setprio(0);
    if (t < NT - 2) asm volatile("s_waitcnt vmcnt(4)" ::: "memory");
    else            asm volatile("s_waitcnt vmcnt(0)" ::: "memory");
    #pragma unroll
    for (int j = 0; j < 4; ++j) Xb[j] = *(const bf16x8*)((const char*)Bs[p ^ 1][0] + bofs[j]);
    #pragma unroll
    for (int i = 0; i < 4; ++i) Xa[i] = *(const bf16x8*)((const char*)As[p ^ 1][0] + aoff + i * 1024);
    if (t + 2 < NT) stage_half<256, K>(Bt, bn0, t + 2, 1, Bs[p][1], tid, sw);
    __builtin_amdgcn_s_barrier();
  }
  asm volatile("s_waitcnt lgkmcnt(0)" ::: "memory");

  // ---------- fused epilogue ----------
  const int nb  = bn0 >> 11;        // 0=q, 1=k, 2=v
  const int rem = bn0 & 2047;
  const int b   = bm0 >> 11;
  const int t0  = bm0 & 2047;
  const int wcb = (wn >> 1) * 128 + (wn & 1) * 32;

  if (nb == 2) {
    #pragma unroll
    for (int i = 0; i < 8; ++i)
      #pragma unroll
      for (int j = 0; j < 4; ++j) {
        int col = rem + wcb + (j >> 1) * 64 + (j & 1) * 16 + lr;
        int head = col >> 7, d = col & 127;
        int tb = t0 + wm * 128 + i * 16 + lg * 4;
        u16x4 st;
        #pragma unroll
        for (int e = 0; e < 4; ++e) st[e] = f2bf(acc[i][j][e]);
        *(u16x4*)(v_t + ((size_t)(b * H_ + head) * D_ + d) * T_ + tb) = st;
      }
  } else {
    unsigned short* dst = nb ? k_r : q_r;
    #pragma unroll
    for (int i = 0; i < 8; ++i)
      #pragma unroll
      for (int j = 0; j < 4; ++j) {
        int col = rem + wcb + (j >> 1) * 64 + (j & 1) * 16 + lr;
        int head = col >> 7, d = col & 127;
        float sgn = (j < 2) ? -1.f : 1.f;
        #pragma unroll
        for (int e = 0; e < 4; ++e) {
          int t = t0 + wm * 128 + i * 16 + lg * 4 + e;
          float c = fcos[t * D_ + d];
          float s = fsin[t * D_ + d];
          float out = acc[i][j][e] * c + sgn * acc[i][j ^ 2][e] * s;
          dst[((size_t)(b * H_ + head) * T_ + t) * D_ + d] = f2bf(out);
        }
      }
  }
}

// ---------- GEMM2: 128x128 tile, 8 waves, dbuf, 2 blocks/CU, counted vmcnt --
// T4 restructure: iter t = [stage(t+1); vmcnt(4) drains tile t (4 older
// ticks), t+1 stays in flight; barrier publishes tile t; reads+MFMA;
// lgkm(0)+barrier seals WAR for next stage]. Invariant entering iter t:
// tile t's 4 ticks outstanding. Tail t=NT-1: vmcnt(0). Every wave issues
// uniform ticks -> per-wave vmcnt + barrier = global drain (R7 rule).
template<int K, int Ntot>
__global__ __launch_bounds__(512, 4) void k_gemmS(const unsigned short* __restrict__ A,
                                                  const unsigned short* __restrict__ Bt,
                                                  float* __restrict__ Cp) {
  __shared__ unsigned short As[2][2][128 * 32];
  __shared__ unsigned short Bs[2][2][128 * 32];
  const int tid = threadIdx.x, lane = tid & 63, wv = tid >> 6;
  const int wm = wv >> 1, wn = wv & 1;
  const int lr = lane & 15, lg = lane >> 4;
  const int sw = tid & 32;
  const int fofs = lr * 64 + ((lg * 16) ^ ((lr & 8) << 2));
  const int aoff = wm * 32 * 64 + fofs;
  const int boff = wn * 64 * 64 + fofs;

  const int nwg = gridDim.x;
  const int nbx = Ntot >> 7;
  const int q = nwg >> 3, r = nwg & 7;
  const int xcd = blockIdx.x & 7, off = blockIdx.x >> 3;
  const int bid = (xcd < r ? xcd * (q + 1) : r * (q + 1) + (xcd - r) * q) + off;
  const int bm0 = (bid / nbx) << 7;
  const int bn0 = (bid % nbx) << 7;

  f32x4 acc[2][4];
  #pragma unroll
  for (int i = 0; i < 2; ++i)
    #pragma unroll
    for (int j = 0; j < 4; ++j)
      #pragma unroll
      for (int e = 0; e < 4; ++e) acc[i][j][e] = 0.f;

  constexpr int NT = K >> 6;

  auto stage_tile = [&](int kt, int rr) {
    stage_half<128, K>(A,  bm0, kt, 0, As[rr][0], tid, sw);
    stage_half<128, K>(Bt, bn0, kt, 0, Bs[rr][0], tid, sw);
    stage_half<128, K>(A,  bm0, kt, 1, As[rr][1], tid, sw);
    stage_half<128, K>(Bt, bn0, kt, 1, Bs[rr][1], tid, sw);
  };

  // prologue: tile0 staged and left outstanding (invariant for iter 0)
  stage_tile(0, 0);

  for (int t = 0; t < NT; ++t) {
    const int p = t & 1;
    if (t + 1 < NT) {
      stage_tile(t + 1, p ^ 1);
      asm volatile("s_waitcnt vmcnt(4)" ::: "memory");   // drain tile t, keep t+1
    } else {
      asm volatile("s_waitcnt vmcnt(0)" ::: "memory");
    }
    __builtin_amdgcn_s_barrier();                        // publish tile t

    bf16x8 af[2], bfr[4];
    #pragma unroll
    for (int kh = 0; kh < 2; ++kh) {
      #pragma unroll
      for (int i = 0; i < 2; ++i) af[i] = *(const bf16x8*)((const char*)As[p][kh] + aoff + i * 1024);
      #pragma unroll
      for (int j = 0; j < 4; ++j) bfr[j] = *(const bf16x8*)((const char*)Bs[p][kh] + boff + j * 1024);
      asm volatile("s_waitcnt lgkmcnt(0)" ::: "memory");
      SB();
      __builtin_amdgcn_s_setprio(1);
      #pragma unroll
      for (int i = 0; i < 2; ++i)
        #pragma unroll
        for (int j = 0; j < 4; ++j)
          acc[i][j] = __builtin_amdgcn_mfma_f32_16x16x32_bf16(af[i], bfr[j], acc[i][j], 0, 0, 0);
      __builtin_amdgcn_s_setprio(0);
    }
    asm volatile("s_waitcnt lgkmcnt(0)" ::: "memory");   // all reads drained
    __builtin_amdgcn_s_barrier();                        // WAR seal for next stage
  }

  #pragma unroll
  for (int i = 0; i < 2; ++i)
    #pragma unroll
    for (int j = 0; j < 4; ++j) {
      int m = bm0 + wm * 32 + i * 16 + lg * 4;
      int n = bn0 + wn * 64 + j * 16 + lr;
      #pragma unroll
      for (int e = 0; e < 4; ++e)
        Cp[(size_t)(m + e) * Ntot + n] = acc[i][j][e];
    }
}

// ---------- attention: 8 waves, q=128/block, 2 barriers/tile (R17 best) -----
__global__ __launch_bounds__(512, 4) void k_attn(const unsigned short* __restrict__ q_r,
                       const unsigned short* __restrict__ k_r,
                       const unsigned short* __restrict__ v_t,
                       unsigned short* __restrict__ y) {
  const int bh = blockIdx.x, b = bh >> 4, h = bh & 15;
  const int q0 = blockIdx.y * 128;
  const int tid = threadIdx.x, lane = tid & 63, wv = tid >> 6;
  const int lr = lane & 15, lg = lane >> 4;

  __shared__ unsigned short Ks[2][64 * 128];
  __shared__ unsigned short Vs[128 * 64];
  __shared__ unsigned short Ps[8 * 16 * 64];

  const size_t bhT = (size_t)(b*H_ + h) * T_;
  const size_t bhD = (size_t)(b*H_ + h) * D_;
  const unsigned short* qbase = q_r + (bhT + q0 + wv*16 + lr) * D_;
  bf16x8 qf[4];
  #pragma unroll
  for (int kk = 0; kk < 4; ++kk) qf[kk] = *(const bf16x8*)(qbase + kk*32 + lg*8);

  f32x4 o[8];
  #pragma unroll
  for (int i = 0; i < 8; ++i)
    #pragma unroll
    for (int e = 0; e < 4; ++e) o[i][e] = 0.f;
  float m_run[4], l_sum[4];
  #pragma unroll
  for (int e = 0; e < 4; ++e) { m_run[e] = -1e30f; l_sum[e] = 0.f; }

  const int i_min = q0 + wv*16, i_max = i_min + 15;
  int kt_lo = q0 - (W_ - 1); if (kt_lo < 0) kt_lo = 0; kt_lo &= ~63;
  const float scale = 0.08838834764831845f;

  unsigned short* Ps_w = Ps + wv * 1024;

  auto stage_k = [&](int kt, int buf) {
    #pragma unroll
    for (int c = 0; c < 2; ++c) {
      int ob = (c * 512 + tid) * 16;
      int row = ob >> 8, slot = (ob >> 4) & 15;
      int cb = slot ^ ((row & 7) << 1);
      gload_lds16(k_r + (bhT + kt + row) * D_ + cb * 8, (char*)Ks[buf] + ob);
    }
  };
  auto stage_v = [&](int kt) {
    #pragma unroll
    for (int c = 0; c < 2; ++c) {
      int ob = (c * 512 + tid) * 16;
      int d = ob >> 7, slot = (ob >> 4) & 7;
      int cb = slot ^ (d & 7);
      gload_lds16(v_t + (bhD + d) * T_ + kt + cb * 8, (char*)Vs + ob);
    }
  };

  stage_k(kt_lo, 0);
  int cur = 0;
  for (int kt = kt_lo; kt < q0 + 128; kt += 64) {
    const bool has_next = (kt + 64 < q0 + 128);
    stage_v(kt);
    if (has_next) stage_k(kt + 64, cur ^ 1);
    if (has_next) asm volatile("s_waitcnt vmcnt(2)" ::: "memory");
    else          asm volatile("s_waitcnt vmcnt(0)" ::: "memory");
    __builtin_amdgcn_s_barrier();

    const bool live = (kt <= i_max) && (kt + 63 >= i_min - (W_ - 1));
    float sv[4][4];
    if (live) {
      const unsigned short* Kc = Ks[cur];
      f32x4 s[4];
      #pragma unroll
      for (int ct = 0; ct < 4; ++ct)
        #pragma unroll
        for (int e = 0; e < 4; ++e) s[ct][e] = 0.f;
      #pragma unroll
      for (int kk = 0; kk < 4; ++kk) {
        #pragma unroll
        for (int ct = 0; ct < 4; ++ct) {
          bf16x8 kf = *(const bf16x8*)&Kc[(ct*16 + lr)*128 + ((kk*4 + lg) ^ ((lr & 7) << 1))*8];
          s[ct] = __builtin_amdgcn_mfma_f32_16x16x32_bf16(qf[kk], kf, s[ct], 0, 0, 0);
        }
      }
      float mnew[4];
      int grow = 0;
      #pragma unroll
      for (int e = 0; e < 4; ++e) {
        int i = i_min + lg*4 + e;
        float rm = -1e30f;
        #pragma unroll
        for (int ct = 0; ct < 4; ++ct) {
          int j = kt + ct*16 + lr;
          bool ok = (j <= i) && (j > i - W_);
          sv[e][ct] = ok ? s[ct][e] * scale : -1e30f;
          rm = fmaxf(rm, sv[e][ct]);
        }
        #pragma unroll
        for (int msk = 1; msk < 16; msk <<= 1) rm = fmaxf(rm, __shfl_xor(rm, msk));
        mnew[e] = fmaxf(m_run[e], rm);
        grow |= (mnew[e] > m_run[e]) ? 1 : 0;
      }
      if (__any(grow)) {
        #pragma unroll
        for (int e = 0; e < 4; ++e) {
          float fac = __expf(m_run[e] - mnew[e]);
          l_sum[e] *= fac;
          m_run[e] = mnew[e];
          #pragma unroll
          for (int nt = 0; nt < 8; ++nt) o[nt][e] *= fac;
        }
      }
      #pragma unroll
      for (int e = 0; e < 4; ++e) {
        int prow = lg*4 + e;
        float rs = 0.f;
        #pragma unroll
        for (int ct = 0; ct < 4; ++ct) {
          float pv = (sv[e][ct] > -1e29f) ? __expf(sv[e][ct] - m_run[e]) : 0.f;
          rs += pv;
          Ps_w[prow*64 + ((ct*2 + (lr >> 3)) ^ (prow & 7))*8 + (lr & 7)] = f2bf(pv);
        }
        #pragma unroll
        for (int msk = 1; msk < 16; msk <<= 1) rs += __shfl_xor(rs, msk);
        l_sum[e] += rs;
      }
      asm volatile("s_waitcnt lgkmcnt(0)" ::: "memory"); SB();
      #pragma unroll
      for (int kk = 0; kk < 2; ++kk) {
        bf16x8 pf = *(const bf16x8*)&Ps_w[lr*64 + ((kk*4 + lg) ^ (lr & 7))*8];
        #pragma unroll
        for (int nt = 0; nt < 8; ++nt) {
          bf16x8 vf = *(const bf16x8*)&Vs[(nt*16 + lr)*64 + ((kk*4 + lg) ^ (lr & 7))*8];
          o[nt] = __builtin_amdgcn_mfma_f32_16x16x32_bf16(pf, vf, o[nt], 0, 0, 0);
        }
      }
    }
    asm volatile("s_waitcnt lgkmcnt(0)" ::: "memory");
    __builtin_amdgcn_s_barrier();
    cur ^= 1;
  }

  #pragma unroll
  for (int nt = 0; nt < 8; ++nt) {
    #pragma unroll
    for (int e = 0; e < 4; ++e) {
      int t = q0 + wv*16 + lg*4 + e;
      int d = nt*16 + lr;
      y[(size_t)(b*T_ + t) * C_ + h*D_ + d] = f2bf(o[nt][e] / l_sum[e]);
    }
  }
}

extern "C" void kernel_launch(void* const* d_in, const int* in_sizes, int n_in,
                              void* d_out, int out_size, void* d_ws, size_t ws_size,
                              hipStream_t stream) {
  const float* x      = (const float*)d_in[0];
  const float* fcos   = (const float*)d_in[1];
  const float* fsin   = (const float*)d_in[2];
  const float* w_attn = (const float*)d_in[3];
  const float* w_proj = (const float*)d_in[4];
  float* out = (float*)d_out;

  char* ws = (char*)d_ws;
  unsigned short* x_bf = (unsigned short*)(ws);
  unsigned short* wa_t = (unsigned short*)(ws + 16777216ull);
  unsigned short* wp_t = (unsigned short*)(ws + 41943040ull);
  unsigned short* q_r  = (unsigned short*)(ws + 100663296ull);
  unsigned short* k_r  = (unsigned short*)(ws + 117440512ull);
  unsigned short* v_t  = (unsigned short*)(ws + 134217728ull);
  unsigned short* y_bf = x_bf;

  k_cvt<<<dim3(4096), dim3(256), 0, stream>>>(x, x_bf, M_*C_);
  k_tcvt<<<dim3(192, 64), dim3(256), 0, stream>>>(w_attn, wa_t, C_, N1_);
  k_tcvt<<<dim3(64, 64), dim3(256), 0, stream>>>(w_proj, wp_t, C_, C_);
  k_gemmF<C_, N1_><<<dim3(384), dim3(512), 0, stream>>>(x_bf, wa_t, fcos, fsin, q_r, k_r, v_t);
  k_attn<<<dim3(32, 16), dim3(512), 0, stream>>>(q_r, k_r, v_t, y_bf);
  k_gemmS<C_, C_><<<dim3(512), dim3(512), 0, stream>>>(y_bf, wp_t, out);
}